// Round 1
// 70.248 us; speedup vs baseline: 1.0657x; 1.0657x over previous
//
#include <hip/hip_runtime.h>

#define B 4
#define N 512
#define DIN 32
#define L 64
#define H 128
#define NB 2
#define R (B * N) // 2048 rows

// ---------------------------------------------------------------------------
// Fused: Z[row,:] = X[row,:]@proj_w + proj_b ; then ylin/xlin for rn block 0.
// 2 rows per workgroup of 256 (128 threads per row).
// Also zeroes out[] (replaces a hipMemsetAsync that cost ~40us/iter).
__global__ void k_proj_lin(const float* __restrict__ X, const float* __restrict__ PW,
                           const float* __restrict__ PB, const float* __restrict__ w1,
                           const float* __restrict__ b1, float* __restrict__ Z,
                           float* __restrict__ ylin, float* __restrict__ xlin,
                           float* __restrict__ out) {
    int r = threadIdx.x / 128;           // local row 0/1
    int t = threadIdx.x % 128;
    int row = blockIdx.x * 2 + r;
    __shared__ float zrow[2][L];

    if (blockIdx.x == 0 && threadIdx.x < B) out[threadIdx.x] = 0.f;

    if (t < L) {
        const float* x = X + row * DIN;
        float acc = PB[t];
#pragma unroll
        for (int k = 0; k < DIN; ++k) acc += x[k] * PW[k * L + t];
        zrow[r][t] = acc;
        Z[row * L + t] = acc;
    }
    __syncthreads();
    float ay = b1[t];  // rb1 folded into ylin
    float ax = 0.f;
#pragma unroll
    for (int k = 0; k < L; ++k) {
        float zv = zrow[r][k];
        ay += zv * w1[k * H + t];
        ax += zv * w1[(L + k) * H + t];
    }
    ylin[row * H + t] = ay;
    xlin[row * H + t] = ax;
}

// ---------------------------------------------------------------------------
// hsum[b,n,h] = sum_m relu(x_lin[b,n,h] + y_lin[b,m,h])
// wg = (b, h-slab of 32, n-slab of 16). Full y slab [512][32] staged in LDS.
// 256 threads: t -> (hl = t&31, n pair = (t>>5)*2). 2 outputs/thread.
__global__ void k_pair(const float* __restrict__ xlin, const float* __restrict__ ylin,
                       float* __restrict__ hsum) {
    __shared__ float ycol[N * 32];  // 64 KB
    int bid = blockIdx.x;
    int b  = bid >> 7;          // / 128
    int rem = bid & 127;
    int h0 = (rem >> 5) * 32;   // 4 h-slabs
    int n0 = (rem & 31) * 16;   // 32 n-slabs
    int t = threadIdx.x;

    // coalesced float4 slab load: ylin[b][m][h0..h0+31] for all m
    const float* ybase = ylin + (size_t)b * N * H + h0;
    for (int i4 = t; i4 < N * 32 / 4; i4 += 256) {
        int m = i4 >> 3;             // (4*i4)/32
        int hl0 = (i4 & 7) * 4;      // (4*i4)%32
        ((float4*)ycol)[i4] = *(const float4*)(ybase + m * H + hl0);
    }
    __syncthreads();

    int hl = t & 31;
    int h = h0 + hl;
    int na = n0 + (t >> 5) * 2;
    int nb = na + 1;
    float xa = xlin[((size_t)b * N + na) * H + h];
    float xb = xlin[((size_t)b * N + nb) * H + h];
    float aa = 0.f, ab = 0.f;
#pragma unroll 8
    for (int m = 0; m < N; ++m) {
        float y = ycol[m * 32 + hl];
        aa += fmaxf(xa + y, 0.f);
        ab += fmaxf(xb + y, 0.f);
    }
    hsum[((size_t)b * N + na) * H + h] = aa;
    hsum[((size_t)b * N + nb) * H + h] = ab;
}

// ---------------------------------------------------------------------------
// Fused per-row tail: Z += hsum@w2 + N*b2 ; Z += relu(Z@fw1+fb1)@fw2 + fb2 ;
// then either lin for the NEXT rn block (FINAL=false) or the pooled decode
// dot into out[b] (FINAL=true). 8 rows per 256-thread wg, weights staged
// stage-by-stage into a 32 KB LDS buffer.
template <bool FINAL>
__global__ void k_post(const float* __restrict__ hsum, const float* __restrict__ w2,
                       const float* __restrict__ b2, const float* __restrict__ fw1,
                       const float* __restrict__ fb1, const float* __restrict__ fw2,
                       const float* __restrict__ fb2, const float* __restrict__ nw1,
                       const float* __restrict__ nb1, float* __restrict__ Z,
                       float* __restrict__ ylin, float* __restrict__ xlin,
                       const float* __restrict__ dw, const float* __restrict__ db,
                       float* __restrict__ out) {
    __shared__ float wbuf[H * L];     // 8192 floats = 32 KB (reused per stage)
    __shared__ float hl_[8][H];       // 4 KB
    __shared__ float zl[8][L];        // 2 KB
    __shared__ float tl[8][H];        // 4 KB
    __shared__ float part[4];

    int t = threadIdx.x;
    int row0 = blockIdx.x * 8;

    // stage inputs (coalesced float4)
    ((float4*)hl_)[t] = ((const float4*)(hsum + (size_t)row0 * H))[t];          // 1024 floats
    if (t < 128) ((float4*)zl)[t] = ((const float4*)(Z + (size_t)row0 * L))[t]; // 512 floats
#pragma unroll
    for (int j = 0; j < 8; ++j)
        ((float4*)wbuf)[t + j * 256] = ((const float4*)w2)[t + j * 256];        // 8192 floats
    __syncthreads();

    // ---- rn_update: zl[r][l] += sum_k hl_[r][k]*w2[k][l] + N*b2[l]
    {
        int l = t & 63;
        int r0 = (t >> 6) * 2, r1 = r0 + 1;
        float a0 = 0.f, a1 = 0.f;
#pragma unroll
        for (int kk = 0; kk < H; kk += 4) {
            float4 h0v = *(float4*)&hl_[r0][kk];
            float4 h1v = *(float4*)&hl_[r1][kk];
            float w0 = wbuf[(kk + 0) * L + l];
            float w1v = wbuf[(kk + 1) * L + l];
            float w2v = wbuf[(kk + 2) * L + l];
            float w3 = wbuf[(kk + 3) * L + l];
            a0 += h0v.x * w0 + h0v.y * w1v + h0v.z * w2v + h0v.w * w3;
            a1 += h1v.x * w0 + h1v.y * w1v + h1v.z * w2v + h1v.w * w3;
        }
        float nb2 = (float)N * b2[l];
        zl[r0][l] += a0 + nb2;
        zl[r1][l] += a1 + nb2;
    }
    __syncthreads();
#pragma unroll
    for (int j = 0; j < 8; ++j)
        ((float4*)wbuf)[t + j * 256] = ((const float4*)fw1)[t + j * 256];
    __syncthreads();

    // ---- fc1: tl[r][h] = relu(sum_l zl[r][l]*fw1[l][h] + fb1[h])
    {
        int h = t & 127;
        int rq = (t >> 7) * 4;
        float acc0 = 0.f, acc1 = 0.f, acc2 = 0.f, acc3 = 0.f;
#pragma unroll
        for (int ll = 0; ll < L; ll += 4) {
            float w0 = wbuf[(ll + 0) * H + h];
            float w1v = wbuf[(ll + 1) * H + h];
            float w2v = wbuf[(ll + 2) * H + h];
            float w3 = wbuf[(ll + 3) * H + h];
            float4 z0 = *(float4*)&zl[rq + 0][ll];
            float4 z1 = *(float4*)&zl[rq + 1][ll];
            float4 z2 = *(float4*)&zl[rq + 2][ll];
            float4 z3 = *(float4*)&zl[rq + 3][ll];
            acc0 += z0.x * w0 + z0.y * w1v + z0.z * w2v + z0.w * w3;
            acc1 += z1.x * w0 + z1.y * w1v + z1.z * w2v + z1.w * w3;
            acc2 += z2.x * w0 + z2.y * w1v + z2.z * w2v + z2.w * w3;
            acc3 += z3.x * w0 + z3.y * w1v + z3.z * w2v + z3.w * w3;
        }
        float bb = fb1[h];
        tl[rq + 0][h] = fmaxf(acc0 + bb, 0.f);
        tl[rq + 1][h] = fmaxf(acc1 + bb, 0.f);
        tl[rq + 2][h] = fmaxf(acc2 + bb, 0.f);
        tl[rq + 3][h] = fmaxf(acc3 + bb, 0.f);
    }
    __syncthreads();
#pragma unroll
    for (int j = 0; j < 8; ++j)
        ((float4*)wbuf)[t + j * 256] = ((const float4*)fw2)[t + j * 256];
    __syncthreads();

    // ---- fc2: zl[r][l] += sum_k tl[r][k]*fw2[k][l] + fb2[l]
    float zfin0, zfin1;  // final z values (for FINAL path)
    int l_ = t & 63;
    int r0_ = (t >> 6) * 2, r1_ = r0_ + 1;
    {
        float a0 = 0.f, a1 = 0.f;
#pragma unroll
        for (int kk = 0; kk < H; kk += 4) {
            float4 t0v = *(float4*)&tl[r0_][kk];
            float4 t1v = *(float4*)&tl[r1_][kk];
            float w0 = wbuf[(kk + 0) * L + l_];
            float w1v = wbuf[(kk + 1) * L + l_];
            float w2v = wbuf[(kk + 2) * L + l_];
            float w3 = wbuf[(kk + 3) * L + l_];
            a0 += t0v.x * w0 + t0v.y * w1v + t0v.z * w2v + t0v.w * w3;
            a1 += t1v.x * w0 + t1v.y * w1v + t1v.z * w2v + t1v.w * w3;
        }
        float bb = fb2[l_];
        zfin0 = zl[r0_][l_] + a0 + bb;
        zfin1 = zl[r1_][l_] + a1 + bb;
    }

    if (FINAL) {
        // pooled decode: out[b] += sum_{r,l} z[r][l]*dw[l]  (+db once per b)
        float v = (zfin0 + zfin1) * dw[l_];
#pragma unroll
        for (int off = 32; off > 0; off >>= 1) v += __shfl_down(v, off);
        if (l_ == 0) part[t >> 6] = v;
        __syncthreads();
        if (t == 0) {
            float s = part[0] + part[1] + part[2] + part[3];
            if ((row0 % N) == 0) s += db[0];
            atomicAdd(out + row0 / N, s);
        }
        return;
    }

    // write back Z, update LDS copy, then lin for next rn block
    __syncthreads();
    zl[r0_][l_] = zfin0;
    zl[r1_][l_] = zfin1;
    Z[(size_t)(row0 + r0_) * L + l_] = zfin0;
    Z[(size_t)(row0 + r1_) * L + l_] = zfin1;
    __syncthreads();

    // lin-y: ylin[row][h] = nb1[h] + sum_k zl[r][k]*nw1[k][h]   (k = 0..L-1)
#pragma unroll
    for (int j = 0; j < 8; ++j)
        ((float4*)wbuf)[t + j * 256] = ((const float4*)nw1)[t + j * 256];
    __syncthreads();
    {
        int h = t & 127;
        int rq = (t >> 7) * 4;
        float acc0 = nb1[h], acc1 = acc0, acc2 = acc0, acc3 = acc0;
#pragma unroll
        for (int kk = 0; kk < L; kk += 4) {
            float w0 = wbuf[(kk + 0) * H + h];
            float w1v = wbuf[(kk + 1) * H + h];
            float w2v = wbuf[(kk + 2) * H + h];
            float w3 = wbuf[(kk + 3) * H + h];
            float4 z0 = *(float4*)&zl[rq + 0][kk];
            float4 z1 = *(float4*)&zl[rq + 1][kk];
            float4 z2 = *(float4*)&zl[rq + 2][kk];
            float4 z3 = *(float4*)&zl[rq + 3][kk];
            acc0 += z0.x * w0 + z0.y * w1v + z0.z * w2v + z0.w * w3;
            acc1 += z1.x * w0 + z1.y * w1v + z1.z * w2v + z1.w * w3;
            acc2 += z2.x * w0 + z2.y * w1v + z2.z * w2v + z2.w * w3;
            acc3 += z3.x * w0 + z3.y * w1v + z3.z * w2v + z3.w * w3;
        }
        ylin[(size_t)(row0 + rq + 0) * H + h] = acc0;
        ylin[(size_t)(row0 + rq + 1) * H + h] = acc1;
        ylin[(size_t)(row0 + rq + 2) * H + h] = acc2;
        ylin[(size_t)(row0 + rq + 3) * H + h] = acc3;
    }
    __syncthreads();
    // lin-x: xlin[row][h] = sum_k zl[r][k]*nw1[L+k][h]
#pragma unroll
    for (int j = 0; j < 8; ++j)
        ((float4*)wbuf)[t + j * 256] = ((const float4*)(nw1 + L * H))[t + j * 256];
    __syncthreads();
    {
        int h = t & 127;
        int rq = (t >> 7) * 4;
        float acc0 = 0.f, acc1 = 0.f, acc2 = 0.f, acc3 = 0.f;
#pragma unroll
        for (int kk = 0; kk < L; kk += 4) {
            float w0 = wbuf[(kk + 0) * H + h];
            float w1v = wbuf[(kk + 1) * H + h];
            float w2v = wbuf[(kk + 2) * H + h];
            float w3 = wbuf[(kk + 3) * H + h];
            float4 z0 = *(float4*)&zl[rq + 0][kk];
            float4 z1 = *(float4*)&zl[rq + 1][kk];
            float4 z2 = *(float4*)&zl[rq + 2][kk];
            float4 z3 = *(float4*)&zl[rq + 3][kk];
            acc0 += z0.x * w0 + z0.y * w1v + z0.z * w2v + z0.w * w3;
            acc1 += z1.x * w0 + z1.y * w1v + z1.z * w2v + z1.w * w3;
            acc2 += z2.x * w0 + z2.y * w1v + z2.z * w2v + z2.w * w3;
            acc3 += z3.x * w0 + z3.y * w1v + z3.z * w2v + z3.w * w3;
        }
        xlin[(size_t)(row0 + rq + 0) * H + h] = acc0;
        xlin[(size_t)(row0 + rq + 1) * H + h] = acc1;
        xlin[(size_t)(row0 + rq + 2) * H + h] = acc2;
        xlin[(size_t)(row0 + rq + 3) * H + h] = acc3;
    }
}

extern "C" void kernel_launch(void* const* d_in, const int* in_sizes, int n_in,
                              void* d_out, int out_size, void* d_ws, size_t ws_size,
                              hipStream_t stream) {
    const float* X      = (const float*)d_in[0];
    const float* proj_w = (const float*)d_in[1];
    const float* proj_b = (const float*)d_in[2];
    const float* rn_w1  = (const float*)d_in[3];
    const float* rn_b1  = (const float*)d_in[4];
    const float* rn_w2  = (const float*)d_in[5];
    const float* rn_b2  = (const float*)d_in[6];
    const float* fc_w1  = (const float*)d_in[7];
    const float* fc_b1  = (const float*)d_in[8];
    const float* fc_w2  = (const float*)d_in[9];
    const float* fc_b2  = (const float*)d_in[10];
    const float* dec_w  = (const float*)d_in[11];
    const float* dec_b  = (const float*)d_in[12];
    float* out = (float*)d_out;

    float* ws   = (float*)d_ws;
    float* Z    = ws;                 // R*L
    float* ylin = Z + R * L;          // R*H
    float* xlin = ylin + R * H;       // R*H
    float* hsum = xlin + R * H;       // R*H

    k_proj_lin<<<R / 2, 256, 0, stream>>>(X, proj_w, proj_b, rn_w1, rn_b1, Z, ylin, xlin, out);
    k_pair<<<512, 256, 0, stream>>>(xlin, ylin, hsum);
    k_post<false><<<R / 8, 256, 0, stream>>>(hsum, rn_w2, rn_b2, fc_w1, fc_b1, fc_w2, fc_b2,
                                             rn_w1 + 2 * L * H, rn_b1 + H, Z, ylin, xlin,
                                             nullptr, nullptr, nullptr);
    k_pair<<<512, 256, 0, stream>>>(xlin, ylin, hsum);
    k_post<true><<<R / 8, 256, 0, stream>>>(hsum, rn_w2 + H * L, rn_b2 + L,
                                            fc_w1 + L * H, fc_b1 + H, fc_w2 + H * L, fc_b2 + L,
                                            nullptr, nullptr, Z, nullptr, nullptr,
                                            dec_w, dec_b, out);
}

// Round 2
// 60.112 us; speedup vs baseline: 1.2454x; 1.1686x over previous
//
#include <hip/hip_runtime.h>
#include <math.h>

#define B 4
#define N 512
#define DIN 32
#define L 64
#define H 128
#define NB 2
#define R (B * N) // 2048 rows

// ---------------------------------------------------------------------------
// Fused: Z[row,:] = X[row,:]@proj_w + proj_b ; then ylin/xlin for rn block 0.
// 2 rows per workgroup of 256 (128 threads per row).
// Also zeroes out[] (replaces a hipMemsetAsync dispatch).
__global__ void k_proj_lin(const float* __restrict__ X, const float* __restrict__ PW,
                           const float* __restrict__ PB, const float* __restrict__ w1,
                           const float* __restrict__ b1, float* __restrict__ Z,
                           float* __restrict__ ylin, float* __restrict__ xlin,
                           float* __restrict__ out) {
    int r = threadIdx.x / 128;           // local row 0/1
    int t = threadIdx.x % 128;
    int row = blockIdx.x * 2 + r;
    __shared__ float zrow[2][L];

    if (blockIdx.x == 0 && threadIdx.x < B) out[threadIdx.x] = 0.f;

    if (t < L) {
        const float* x = X + row * DIN;
        float acc = PB[t];
#pragma unroll
        for (int k = 0; k < DIN; ++k) acc += x[k] * PW[k * L + t];
        zrow[r][t] = acc;
        Z[row * L + t] = acc;
    }
    __syncthreads();
    float ay = b1[t];  // rb1 folded into ylin
    float ax = 0.f;
#pragma unroll
    for (int k = 0; k < L; ++k) {
        float zv = zrow[r][k];
        ay += zv * w1[k * H + t];
        ax += zv * w1[(L + k) * H + t];
    }
    ylin[row * H + t] = ay;
    xlin[row * H + t] = ax;
}

// ---------------------------------------------------------------------------
// hsum[b,n,h] = sum_m relu(x_lin[b,n,h] + y_lin[b,m,h])
// Sort-based: per (b,h) block, bitonic-sort the 512 y values in LDS, build
// suffix sums, then each n is a 10-step branchless binary search:
//   cnt = #{ y > -x },  hsum = cnt*x + sum_{y > -x} y.
// relu zeros contribute exactly 0.0f so the selection is exact; only the
// summation order changes vs the naive loop.
__global__ void k_pairsort(const float* __restrict__ xlin, const float* __restrict__ ylin,
                           float* __restrict__ hsum) {
    __shared__ float ys[1024];   // sorted y (512) + INF padding (512) for search
    __shared__ float ss[N + 1];  // suffix sums: ss[i] = sum_{j>=i} ys[j], ss[N]=0
    __shared__ float csum[64];
    __shared__ float csuf[65];

    int t = threadIdx.x;
    int b = blockIdx.x >> 7;     // / H
    int h = blockIdx.x & 127;    // % H

    // load y column (stride H) and pad upper half with +INF sentinels
    const float* ycol = ylin + (size_t)b * N * H + h;
    for (int m = t; m < N; m += 256) ys[m] = ycol[(size_t)m * H];
    for (int m = N + t; m < 1024; m += 256) ys[m] = INFINITY;
    __syncthreads();

    // bitonic sort ascending on ys[0..511] (256 threads, one pair each/round)
    for (int k = 2; k <= N; k <<= 1) {
        for (int j = k >> 1; j > 0; j >>= 1) {
            int i = ((t & ~(j - 1)) << 1) | (t & (j - 1));
            int p = i | j;
            float a = ys[i], c = ys[p];
            bool up = (i & k) == 0;
            if ((a > c) == up) { ys[i] = c; ys[p] = a; }
            __syncthreads();
        }
    }

    // suffix sums: 64 chunk sums, sequential chunk suffix-scan, then fill
    if (t < 64) {
        float s = 0.f;
        int base = t * 8;
#pragma unroll
        for (int q = 7; q >= 0; --q) s += ys[base + q];
        csum[t] = s;
    }
    __syncthreads();
    if (t == 0) {
        csuf[64] = 0.f;
        float run = 0.f;
        for (int c = 63; c >= 0; --c) { run += csum[c]; csuf[c] = run; }
    }
    __syncthreads();
    for (int i = t; i < N; i += 256) {
        float s = csuf[(i >> 3) + 1];
        int e = i | 7;
        for (int q = e; q >= i; --q) s += ys[q];
        ss[i] = s;
    }
    if (t == 0) ss[N] = 0.f;
    __syncthreads();

    // per-n: branchless lower-bound (count of y <= -x), two searches in flight
    const float* xcol = xlin + (size_t)b * N * H + h;
    float* ocol = hsum + (size_t)b * N * H + h;
    int n0 = t, n1 = t + 256;
    float x0 = xcol[(size_t)n0 * H];
    float x1 = xcol[(size_t)n1 * H];
    float v0 = -x0, v1 = -x1;
    int p0 = 0, p1 = 0;
#pragma unroll
    for (int s = 512; s >= 1; s >>= 1) {
        if (ys[p0 + s - 1] <= v0) p0 += s;
        if (ys[p1 + s - 1] <= v1) p1 += s;
    }
    ocol[(size_t)n0 * H] = (float)(N - p0) * x0 + ss[p0];
    ocol[(size_t)n1 * H] = (float)(N - p1) * x1 + ss[p1];
}

// ---------------------------------------------------------------------------
// Fused per-row tail: Z += hsum@w2 + N*b2 ; Z += relu(Z@fw1+fb1)@fw2 + fb2 ;
// then either lin for the NEXT rn block (FINAL=false) or the pooled decode
// dot into out[b] (FINAL=true). 8 rows per 256-thread wg, weights staged
// stage-by-stage into a 32 KB LDS buffer.
template <bool FINAL>
__global__ void k_post(const float* __restrict__ hsum, const float* __restrict__ w2,
                       const float* __restrict__ b2, const float* __restrict__ fw1,
                       const float* __restrict__ fb1, const float* __restrict__ fw2,
                       const float* __restrict__ fb2, const float* __restrict__ nw1,
                       const float* __restrict__ nb1, float* __restrict__ Z,
                       float* __restrict__ ylin, float* __restrict__ xlin,
                       const float* __restrict__ dw, const float* __restrict__ db,
                       float* __restrict__ out) {
    __shared__ float wbuf[H * L];     // 8192 floats = 32 KB (reused per stage)
    __shared__ float hl_[8][H];       // 4 KB
    __shared__ float zl[8][L];        // 2 KB
    __shared__ float tl[8][H];        // 4 KB
    __shared__ float part[4];

    int t = threadIdx.x;
    int row0 = blockIdx.x * 8;

    // stage inputs (coalesced float4)
    ((float4*)hl_)[t] = ((const float4*)(hsum + (size_t)row0 * H))[t];          // 1024 floats
    if (t < 128) ((float4*)zl)[t] = ((const float4*)(Z + (size_t)row0 * L))[t]; // 512 floats
#pragma unroll
    for (int j = 0; j < 8; ++j)
        ((float4*)wbuf)[t + j * 256] = ((const float4*)w2)[t + j * 256];        // 8192 floats
    __syncthreads();

    // ---- rn_update: zl[r][l] += sum_k hl_[r][k]*w2[k][l] + N*b2[l]
    {
        int l = t & 63;
        int r0 = (t >> 6) * 2, r1 = r0 + 1;
        float a0 = 0.f, a1 = 0.f;
#pragma unroll
        for (int kk = 0; kk < H; kk += 4) {
            float4 h0v = *(float4*)&hl_[r0][kk];
            float4 h1v = *(float4*)&hl_[r1][kk];
            float w0 = wbuf[(kk + 0) * L + l];
            float w1v = wbuf[(kk + 1) * L + l];
            float w2v = wbuf[(kk + 2) * L + l];
            float w3 = wbuf[(kk + 3) * L + l];
            a0 += h0v.x * w0 + h0v.y * w1v + h0v.z * w2v + h0v.w * w3;
            a1 += h1v.x * w0 + h1v.y * w1v + h1v.z * w2v + h1v.w * w3;
        }
        float nb2 = (float)N * b2[l];
        zl[r0][l] += a0 + nb2;
        zl[r1][l] += a1 + nb2;
    }
    __syncthreads();
#pragma unroll
    for (int j = 0; j < 8; ++j)
        ((float4*)wbuf)[t + j * 256] = ((const float4*)fw1)[t + j * 256];
    __syncthreads();

    // ---- fc1: tl[r][h] = relu(sum_l zl[r][l]*fw1[l][h] + fb1[h])
    {
        int h = t & 127;
        int rq = (t >> 7) * 4;
        float acc0 = 0.f, acc1 = 0.f, acc2 = 0.f, acc3 = 0.f;
#pragma unroll
        for (int ll = 0; ll < L; ll += 4) {
            float w0 = wbuf[(ll + 0) * H + h];
            float w1v = wbuf[(ll + 1) * H + h];
            float w2v = wbuf[(ll + 2) * H + h];
            float w3 = wbuf[(ll + 3) * H + h];
            float4 z0 = *(float4*)&zl[rq + 0][ll];
            float4 z1 = *(float4*)&zl[rq + 1][ll];
            float4 z2 = *(float4*)&zl[rq + 2][ll];
            float4 z3 = *(float4*)&zl[rq + 3][ll];
            acc0 += z0.x * w0 + z0.y * w1v + z0.z * w2v + z0.w * w3;
            acc1 += z1.x * w0 + z1.y * w1v + z1.z * w2v + z1.w * w3;
            acc2 += z2.x * w0 + z2.y * w1v + z2.z * w2v + z2.w * w3;
            acc3 += z3.x * w0 + z3.y * w1v + z3.z * w2v + z3.w * w3;
        }
        float bb = fb1[h];
        tl[rq + 0][h] = fmaxf(acc0 + bb, 0.f);
        tl[rq + 1][h] = fmaxf(acc1 + bb, 0.f);
        tl[rq + 2][h] = fmaxf(acc2 + bb, 0.f);
        tl[rq + 3][h] = fmaxf(acc3 + bb, 0.f);
    }
    __syncthreads();
#pragma unroll
    for (int j = 0; j < 8; ++j)
        ((float4*)wbuf)[t + j * 256] = ((const float4*)fw2)[t + j * 256];
    __syncthreads();

    // ---- fc2: zl[r][l] += sum_k tl[r][k]*fw2[k][l] + fb2[l]
    float zfin0, zfin1;  // final z values (for FINAL path)
    int l_ = t & 63;
    int r0_ = (t >> 6) * 2, r1_ = r0_ + 1;
    {
        float a0 = 0.f, a1 = 0.f;
#pragma unroll
        for (int kk = 0; kk < H; kk += 4) {
            float4 t0v = *(float4*)&tl[r0_][kk];
            float4 t1v = *(float4*)&tl[r1_][kk];
            float w0 = wbuf[(kk + 0) * L + l_];
            float w1v = wbuf[(kk + 1) * L + l_];
            float w2v = wbuf[(kk + 2) * L + l_];
            float w3 = wbuf[(kk + 3) * L + l_];
            a0 += t0v.x * w0 + t0v.y * w1v + t0v.z * w2v + t0v.w * w3;
            a1 += t1v.x * w0 + t1v.y * w1v + t1v.z * w2v + t1v.w * w3;
        }
        float bb = fb2[l_];
        zfin0 = zl[r0_][l_] + a0 + bb;
        zfin1 = zl[r1_][l_] + a1 + bb;
    }

    if (FINAL) {
        // pooled decode: out[b] += sum_{r,l} z[r][l]*dw[l]  (+db once per b)
        float v = (zfin0 + zfin1) * dw[l_];
#pragma unroll
        for (int off = 32; off > 0; off >>= 1) v += __shfl_down(v, off);
        if (l_ == 0) part[t >> 6] = v;
        __syncthreads();
        if (t == 0) {
            float s = part[0] + part[1] + part[2] + part[3];
            if ((row0 % N) == 0) s += db[0];
            atomicAdd(out + row0 / N, s);
        }
        return;
    }

    // write back Z, update LDS copy, then lin for next rn block
    __syncthreads();
    zl[r0_][l_] = zfin0;
    zl[r1_][l_] = zfin1;
    Z[(size_t)(row0 + r0_) * L + l_] = zfin0;
    Z[(size_t)(row0 + r1_) * L + l_] = zfin1;
    __syncthreads();

    // lin-y: ylin[row][h] = nb1[h] + sum_k zl[r][k]*nw1[k][h]   (k = 0..L-1)
#pragma unroll
    for (int j = 0; j < 8; ++j)
        ((float4*)wbuf)[t + j * 256] = ((const float4*)nw1)[t + j * 256];
    __syncthreads();
    {
        int h = t & 127;
        int rq = (t >> 7) * 4;
        float acc0 = nb1[h], acc1 = acc0, acc2 = acc0, acc3 = acc0;
#pragma unroll
        for (int kk = 0; kk < L; kk += 4) {
            float w0 = wbuf[(kk + 0) * H + h];
            float w1v = wbuf[(kk + 1) * H + h];
            float w2v = wbuf[(kk + 2) * H + h];
            float w3 = wbuf[(kk + 3) * H + h];
            float4 z0 = *(float4*)&zl[rq + 0][kk];
            float4 z1 = *(float4*)&zl[rq + 1][kk];
            float4 z2 = *(float4*)&zl[rq + 2][kk];
            float4 z3 = *(float4*)&zl[rq + 3][kk];
            acc0 += z0.x * w0 + z0.y * w1v + z0.z * w2v + z0.w * w3;
            acc1 += z1.x * w0 + z1.y * w1v + z1.z * w2v + z1.w * w3;
            acc2 += z2.x * w0 + z2.y * w1v + z2.z * w2v + z2.w * w3;
            acc3 += z3.x * w0 + z3.y * w1v + z3.z * w2v + z3.w * w3;
        }
        ylin[(size_t)(row0 + rq + 0) * H + h] = acc0;
        ylin[(size_t)(row0 + rq + 1) * H + h] = acc1;
        ylin[(size_t)(row0 + rq + 2) * H + h] = acc2;
        ylin[(size_t)(row0 + rq + 3) * H + h] = acc3;
    }
    __syncthreads();
    // lin-x: xlin[row][h] = sum_k zl[r][k]*nw1[L+k][h]
#pragma unroll
    for (int j = 0; j < 8; ++j)
        ((float4*)wbuf)[t + j * 256] = ((const float4*)(nw1 + L * H))[t + j * 256];
    __syncthreads();
    {
        int h = t & 127;
        int rq = (t >> 7) * 4;
        float acc0 = 0.f, acc1 = 0.f, acc2 = 0.f, acc3 = 0.f;
#pragma unroll
        for (int kk = 0; kk < L; kk += 4) {
            float w0 = wbuf[(kk + 0) * H + h];
            float w1v = wbuf[(kk + 1) * H + h];
            float w2v = wbuf[(kk + 2) * H + h];
            float w3 = wbuf[(kk + 3) * H + h];
            float4 z0 = *(float4*)&zl[rq + 0][kk];
            float4 z1 = *(float4*)&zl[rq + 1][kk];
            float4 z2 = *(float4*)&zl[rq + 2][kk];
            float4 z3 = *(float4*)&zl[rq + 3][kk];
            acc0 += z0.x * w0 + z0.y * w1v + z0.z * w2v + z0.w * w3;
            acc1 += z1.x * w0 + z1.y * w1v + z1.z * w2v + z1.w * w3;
            acc2 += z2.x * w0 + z2.y * w1v + z2.z * w2v + z2.w * w3;
            acc3 += z3.x * w0 + z3.y * w1v + z3.z * w2v + z3.w * w3;
        }
        xlin[(size_t)(row0 + rq + 0) * H + h] = acc0;
        xlin[(size_t)(row0 + rq + 1) * H + h] = acc1;
        xlin[(size_t)(row0 + rq + 2) * H + h] = acc2;
        xlin[(size_t)(row0 + rq + 3) * H + h] = acc3;
    }
}

extern "C" void kernel_launch(void* const* d_in, const int* in_sizes, int n_in,
                              void* d_out, int out_size, void* d_ws, size_t ws_size,
                              hipStream_t stream) {
    const float* X      = (const float*)d_in[0];
    const float* proj_w = (const float*)d_in[1];
    const float* proj_b = (const float*)d_in[2];
    const float* rn_w1  = (const float*)d_in[3];
    const float* rn_b1  = (const float*)d_in[4];
    const float* rn_w2  = (const float*)d_in[5];
    const float* rn_b2  = (const float*)d_in[6];
    const float* fc_w1  = (const float*)d_in[7];
    const float* fc_b1  = (const float*)d_in[8];
    const float* fc_w2  = (const float*)d_in[9];
    const float* fc_b2  = (const float*)d_in[10];
    const float* dec_w  = (const float*)d_in[11];
    const float* dec_b  = (const float*)d_in[12];
    float* out = (float*)d_out;

    float* ws   = (float*)d_ws;
    float* Z    = ws;                 // R*L
    float* ylin = Z + R * L;          // R*H
    float* xlin = ylin + R * H;       // R*H
    float* hsum = xlin + R * H;       // R*H

    k_proj_lin<<<R / 2, 256, 0, stream>>>(X, proj_w, proj_b, rn_w1, rn_b1, Z, ylin, xlin, out);
    k_pairsort<<<B * H, 256, 0, stream>>>(xlin, ylin, hsum);
    k_post<false><<<R / 8, 256, 0, stream>>>(hsum, rn_w2, rn_b2, fc_w1, fc_b1, fc_w2, fc_b2,
                                             rn_w1 + 2 * L * H, rn_b1 + H, Z, ylin, xlin,
                                             nullptr, nullptr, nullptr);
    k_pairsort<<<B * H, 256, 0, stream>>>(xlin, ylin, hsum);
    k_post<true><<<R / 8, 256, 0, stream>>>(hsum, rn_w2 + H * L, rn_b2 + L,
                                            fc_w1 + L * H, fc_b1 + H, fc_w2 + H * L, fc_b2 + L,
                                            nullptr, nullptr, Z, nullptr, nullptr,
                                            dec_w, dec_b, out);
}